// Round 1
// baseline (152.717 us; speedup 1.0000x reference)
//
#include <hip/hip_runtime.h>
#include <math.h>

// AntiAliasInterpolation2d: 13x13 separable gaussian blur (sigma=1.5, zero-pad 6)
// + nearest 4x downsample, fused. x: (32,512,512,3) f32 -> out: (32,128,128,3) f32.
//
// out[n,i,j,c] = sum_{dy,dx in [-6,6]} w[dy]*w[dx] * x[n, 4i+dy, 4j+dx, c]
//
// Phase-rotated accumulator scheme: input rows grouped in quads y=4q+p (p=0..3).
// Row phase p contributes to output rows i = q-1..q+2 with STATIC dy:
//   p=0: A0+=w10*h, A1+=w6*h, A2+=w2*h
//   p=1: A0+=w11*h, A1+=w7*h, A2+=w3*h
//   p=2: A0+=w12*h, A1+=w8*h, A2+=w4*h, A3+=w0*h
//   p=3:            A1+=w9*h, A2+=w5*h, A3+=w1*h
// After quad q, A0 (= output row q-1) is complete; rotate A0<-A1<-A2<-A3<-0.

namespace {
constexpr int N_IMG    = 32;
constexpr int H_IN     = 512;
constexpr int W_IN     = 512;
constexpr int C_CH     = 3;
constexpr int H_OUT    = 128;
constexpr int W_OUT    = 128;
constexpr int T_ROWS   = 8;                 // output rows per block (band)
constexpr int BANDS    = H_OUT / T_ROWS;    // 16
constexpr int PITCH    = 532;               // floats per channel plane; %4==0; >=524
constexpr int ROW_ELEMS = W_IN * C_CH;      // 1536
constexpr int NTHREADS = 384;               // one thread per (j,c) output lane
constexpr int LDS_FLOATS = 2 * 4 * 3 * PITCH; // 2 buffers x 4 rows x 3 planes
}

__global__ __launch_bounds__(NTHREADS, 3)
void aa_blur_down(const float* __restrict__ in, float* __restrict__ out) {
  // lds[((b*4 + p)*3 + c)*PITCH + (x + 8)]  -- planar per-channel rows,
  // x in [-8, 524): 8-float front halo keeps the 4*j window float4-aligned.
  __shared__ __align__(16) float lds[LDS_FLOATS];

  const int tid = threadIdx.x;
  const int j   = tid / 3;      // output column 0..127
  const int c   = tid % 3;      // channel
  const int n    = blockIdx.x / BANDS;
  const int band = blockIdx.x % BANDS;
  const int i0   = band * T_ROWS;

  // normalized 1D gaussian weights (13 taps), all-static use -> registers
  float wt[13];
  {
    float s = 0.f;
#pragma unroll
    for (int r = 0; r < 13; ++r) {
      const float d = (float)r - 6.0f;
      wt[r] = expf(-d * d * (1.0f / 4.5f));
      s += wt[r];
    }
    const float inv = 1.0f / s;
#pragma unroll
    for (int r = 0; r < 13; ++r) wt[r] *= inv;
  }

  const int qstart = i0 - 2;          // first quad feeding output row i0
  const int qend   = i0 + T_ROWS;     // last quad feeding output row i0+T-1
  const float* img = in + (size_t)n * H_IN * ROW_ELEMS;

  // zero the whole LDS once: establishes the x-halo zeros (zero padding)
  for (int idx = tid; idx < LDS_FLOATS; idx += NTHREADS) lds[idx] = 0.f;
  __syncthreads();

  float pre[16]; // prefetch registers: 4 rows x 4 elements per thread

  // element e = tid + 384*k of the quad's 4*1536 floats:
  //   row p = k>>2, inner = tid + 384*(k&3); since 384%3==0:
  //   channel = tid%3 = c, x = j + 128*(k&3)  -> clean planar LDS writes
  auto load_quad = [&](int q) {
#pragma unroll
    for (int k = 0; k < 16; ++k) {
      const int y = 4 * q + (k >> 2);
      if (y >= 0 && y < H_IN) {       // wave-uniform predicate (zero row padding)
        pre[k] = img[(size_t)y * ROW_ELEMS + tid + NTHREADS * (k & 3)];
      } else {
        pre[k] = 0.f;
      }
    }
  };

  auto store_quad = [&](int b) {
#pragma unroll
    for (int k = 0; k < 16; ++k) {
      const int p = k >> 2;
      lds[((b * 4 + p) * 3 + c) * PITCH + j + 128 * (k & 3) + 8] = pre[k];
    }
  };

  load_quad(qstart);
  store_quad(0);
  __syncthreads();

  float A0 = 0.f, A1 = 0.f, A2 = 0.f, A3 = 0.f;

  for (int q = qstart; q <= qend; ++q) {
    const int b = (q - qstart) & 1;
    const bool more = (q < qend);
    if (more) load_quad(q + 1);       // prefetch next quad during compute

    // horizontal 13-tap conv for the 4 rows of this quad
    float h[4];
#pragma unroll
    for (int p = 0; p < 4; ++p) {
      const float* plane = &lds[((b * 4 + p) * 3 + c) * PITCH + 4 * j];
      float win[16];                  // x in [4j-8, 4j+8), taps at win[2..14]
      *reinterpret_cast<float4*>(&win[0])  = *reinterpret_cast<const float4*>(&plane[0]);
      *reinterpret_cast<float4*>(&win[4])  = *reinterpret_cast<const float4*>(&plane[4]);
      *reinterpret_cast<float4*>(&win[8])  = *reinterpret_cast<const float4*>(&plane[8]);
      *reinterpret_cast<float4*>(&win[12]) = *reinterpret_cast<const float4*>(&plane[12]);
      float hh = 0.f;
#pragma unroll
      for (int dx = 0; dx < 13; ++dx) hh = fmaf(wt[dx], win[2 + dx], hh);
      h[p] = hh;
    }

    // vertical accumulation, all weights static
    A0 = fmaf(wt[10], h[0], A0); A0 = fmaf(wt[11], h[1], A0); A0 = fmaf(wt[12], h[2], A0);
    A1 = fmaf(wt[6],  h[0], A1); A1 = fmaf(wt[7],  h[1], A1); A1 = fmaf(wt[8],  h[2], A1); A1 = fmaf(wt[9], h[3], A1);
    A2 = fmaf(wt[2],  h[0], A2); A2 = fmaf(wt[3],  h[1], A2); A2 = fmaf(wt[4],  h[2], A2); A2 = fmaf(wt[5], h[3], A2);
    A3 = fmaf(wt[0],  h[2], A3); A3 = fmaf(wt[1],  h[3], A3);

    // output row q-1 is complete after this quad
    const int i_out = q - 1;
    if (i_out >= i0) {                // i_out <= i0+T-1 always holds
      out[(size_t)(n * H_OUT + i_out) * (W_OUT * C_CH) + tid] = A0;
    }
    A0 = A1; A1 = A2; A2 = A3; A3 = 0.f;

    if (more) store_quad(b ^ 1);      // fill the other buffer
    __syncthreads();                  // one barrier per quad (double-buffered)
  }
}

extern "C" void kernel_launch(void* const* d_in, const int* in_sizes, int n_in,
                              void* d_out, int out_size, void* d_ws, size_t ws_size,
                              hipStream_t stream) {
  const float* x = (const float*)d_in[0];
  float* out = (float*)d_out;
  (void)in_sizes; (void)n_in; (void)out_size; (void)d_ws; (void)ws_size;
  hipLaunchKernelGGL(aa_blur_down, dim3(N_IMG * BANDS), dim3(NTHREADS), 0, stream, x, out);
}